// Round 7
// baseline (218.390 us; speedup 1.0000x reference)
//
#include <hip/hip_runtime.h>
#include <hip/hip_bf16.h>

// Problem constants (fixed by reference)
static constexpr int Nn  = 8192;     // nodes
static constexpr int Hh  = 4;        // heads
static constexpr int Ee  = 131072;   // edges
static constexpr int DK  = 16;       // per-head feature dim
static constexpr int CAP = 128;      // per-row bucket capacity; deg ~ Poisson(32),
                                     // P(>=128) ~ 1e-40 — guarded anyway
static constexpr int XLEN = Hh * Nn * DK;  // 524288 floats
// State layout is [hd][m][k] flat = hd*131072 + m*16 + k — EXACTLY the flat
// order of h.reshape(H,N,16) and of result.reshape(N,64). Verified rounds 2/4/6.
// NOTE (round 5 post-mortem): do NOT fuse sweeps with cg::grid_sync — each sync
// costs ~115us on gfx950 (cross-XCD L2 flush + 1024-block spin). Kernel
// boundaries are the cheap grid barrier here.
// Packed directed entry: (t<<13)|v, t in [0,2E)=2^18, v in [0,2^13). For equal
// v, packed order == t order == numpy last-write-wins rank.

// ---------------------------------------------------------------------------
// Kernel 1: scatter all 2E directed entries into per-row buckets (4B packed).
//   t < E : (src,dst) first scatter; t >= E : (dst,src) second scatter.
__global__ void scatter_kernel(const int* __restrict__ src, const int* __restrict__ dst,
                               int* __restrict__ cnt, unsigned* __restrict__ bucket) {
    int t = blockIdx.x * blockDim.x + threadIdx.x;
    if (t >= 2 * Ee) return;
    int u, v;
    if (t < Ee) { u = src[t]; v = dst[t]; }
    else        { u = dst[t - Ee]; v = src[t - Ee]; }
    int pos = atomicAdd(&cnt[u], 1);
    if (pos < CAP) bucket[u * CAP + pos] = ((unsigned)t << 13) | (unsigned)v;
}

// ---------------------------------------------------------------------------
// Kernel 2: per-row dedup (last-write-wins = max packed per v) + rowsum +
// normalize. One wave per row; entries -> LDS; O(d^2) survival scan;
// ballot-compact; 4-head shfl rowsum; write col element-offsets + val4.
__global__ void __launch_bounds__(256)
dedup_kernel(const int* __restrict__ cnt, const unsigned* __restrict__ bucket,
             const float* __restrict__ e, int* __restrict__ cnt2,
             int* __restrict__ cols, float* __restrict__ val4) {
    __shared__ unsigned lp[4][CAP];
    int w = threadIdx.x >> 6;
    int lane = threadIdx.x & 63;
    int u = blockIdx.x * 4 + w;
    int d = cnt[u]; if (d > CAP) d = CAP;

    for (int i = lane; i < d; i += 64)
        lp[w][i] = bucket[u * CAP + i];
    __syncthreads();

    // survival + per-head partial rowsums (each lane owns entries lane, lane+64)
    bool  surv[2] = {false, false};
    int   vv[2];
    float ev[2][4];
    float s0 = 0.f, s1 = 0.f, s2 = 0.f, s3 = 0.f;
#pragma unroll
    for (int r = 0; r < 2; r++) {
        int i = lane + 64 * r;
        if (i < d) {
            unsigned pi = lp[w][i];
            unsigned vi = pi & 8191u;
            bool alive = true;
            for (int j = 0; j < d; j++) {
                unsigned pj = lp[w][j];
                if ((pj & 8191u) == vi && pj > pi) { alive = false; break; }
            }
            surv[r] = alive;
            vv[r] = (int)vi;
            if (alive) {
                int t = (int)(pi >> 13);
                int edge = (t >= Ee) ? (t - Ee) : t;
                ev[r][0] = e[0 * Ee + edge];
                ev[r][1] = e[1 * Ee + edge];
                ev[r][2] = e[2 * Ee + edge];
                ev[r][3] = e[3 * Ee + edge];
                s0 += ev[r][0]; s1 += ev[r][1]; s2 += ev[r][2]; s3 += ev[r][3];
            }
        }
    }
#pragma unroll
    for (int off = 32; off > 0; off >>= 1) {
        s0 += __shfl_xor(s0, off, 64);
        s1 += __shfl_xor(s1, off, 64);
        s2 += __shfl_xor(s2, off, 64);
        s3 += __shfl_xor(s3, off, 64);
    }
    float i0 = 1.f / s0, i1 = 1.f / s1, i2 = 1.f / s2, i3 = 1.f / s3;

    // ballot-compact survivors to packed positions
    unsigned long long m0 = __ballot(surv[0]);
    unsigned long long m1 = __ballot(surv[1]);
    unsigned long long below = ((unsigned long long)1 << lane) - 1;
    int base1 = __popcll(m0);
    int pos[2];
    pos[0] = __popcll(m0 & below);
    pos[1] = base1 + __popcll(m1 & below);
    int total = base1 + __popcll(m1);
#pragma unroll
    for (int r = 0; r < 2; r++) {
        if (surv[r]) {
            int q = u * CAP + pos[r];
            cols[q] = vv[r] * DK;           // element offset into a head's x
            val4[4 * q + 0] = ev[r][0] * i0;
            val4[4 * q + 1] = ev[r][1] * i1;
            val4[4 * q + 2] = ev[r][2] * i2;
            val4[4 * q + 3] = ev[r][3] * i3;
        }
    }
    if (lane == 0) cnt2[u] = total;
}

// ---------------------------------------------------------------------------
// Kernel 3: one Horner sweep, split-K.  xn = s_k * (a_norm @ x) + c_k * h
// One block (4 waves) per row; wave w takes entries w, w+4, ... (dependent
// chain per wave = d/4 ~ 8 iters); LDS cross-wave reduce; wave 0 writes.
__global__ void __launch_bounds__(256)
spmv_kernel(const int* __restrict__ cnt2, const int* __restrict__ cols,
            const float* __restrict__ val4, const float* __restrict__ x,
            const float* __restrict__ h, float* __restrict__ xn,
            float s_k, float c_k) {
    __shared__ float part[4][64];
    int u = blockIdx.x;
    int w = threadIdx.x >> 6;
    int lane = threadIdx.x & 63;
    int hd = lane >> 4, k = lane & 15;
    int d = cnt2[u];
    int base = u * CAP;
    const float* xh = x + hd * (Nn * DK) + k;
    float acc = 0.f;
    for (int p = base + w; p < base + d; p += 4)
        acc += val4[4 * p + hd] * xh[cols[p]];
    part[w][lane] = acc;
    __syncthreads();
    if (w == 0) {
        acc = part[0][lane] + part[1][lane] + part[2][lane] + part[3][lane];
        int oi = (hd * Nn + u) * DK + k;
        xn[oi] = s_k * acc + c_k * h[oi];
    }
}

// ---------------------------------------------------------------------------
extern "C" void kernel_launch(void* const* d_in, const int* in_sizes, int n_in,
                              void* d_out, int out_size, void* d_ws, size_t ws_size,
                              hipStream_t stream) {
    const float* h = (const float*)d_in[0];
    const float* e = (const float*)d_in[1];
    const int* src = (const int*)d_in[2];
    const int* dst = (const int*)d_in[3];
    float* out = (float*)d_out;

    // Workspace carve-up (~29 MB)
    char* ws = (char*)d_ws;
    size_t off = 0;
    auto alloc = [&](size_t bytes) -> void* {
        void* p = ws + off;
        off = (off + bytes + 255) & ~(size_t)255;
        return p;
    };
    int*      cnts   = (int*)     alloc((size_t)2 * Nn * 4);        // [cnt | cnt2]
    int*      cnt    = cnts;
    int*      cnt2   = cnts + Nn;
    unsigned* bucket = (unsigned*)alloc((size_t)Nn * CAP * 4);      // 4 MB
    int*      cols   = (int*)     alloc((size_t)Nn * CAP * 4);      // 4 MB
    float*    val4   = (float*)   alloc((size_t)Nn * CAP * 4 * 4);  // 16 MB
    float*    bufA   = (float*)   alloc((size_t)XLEN * 4);          // 2 MB
    float*    bufB   = (float*)   alloc((size_t)XLEN * 4);          // 2 MB

    const int tpb = 256;

    hipMemsetAsync(cnts, 0, (size_t)2 * Nn * 4, stream);
    scatter_kernel<<<(2 * Ee) / tpb, tpb, 0, stream>>>(src, dst, cnt, bucket);
    dedup_kernel<<<Nn / 4, tpb, 0, stream>>>(cnt, bucket, e, cnt2, cols, val4);

    // Horner: r = (1/720) a h + (1/120) h; then r = a r + h/24; ... ; r = a r + h
    const float s_k[6] = {1.f / 720.f, 1.f, 1.f, 1.f, 1.f, 1.f};
    const float c_k[6] = {1.f / 120.f, 1.f / 24.f, 1.f / 6.f, 0.5f, 1.f, 1.f};
    const float* xp = h;
    float* bufs[2] = {bufA, bufB};
    for (int i = 0; i < 6; i++) {
        float* xn = (i == 5) ? out : bufs[i & 1];
        spmv_kernel<<<Nn, tpb, 0, stream>>>(cnt2, cols, val4, xp, h, xn, s_k[i], c_k[i]);
        xp = xn;
    }
}

// Round 8
// 145.998 us; speedup vs baseline: 1.4958x; 1.4958x over previous
//
#include <hip/hip_runtime.h>
#include <hip/hip_bf16.h>

// Problem constants (fixed by reference)
static constexpr int Nn  = 8192;     // nodes
static constexpr int Hh  = 4;        // heads
static constexpr int Ee  = 131072;   // edges
static constexpr int DK  = 16;       // per-head feature dim
static constexpr int CAP = 128;      // per-row bucket capacity; deg ~ Poisson(32)
static constexpr int XLEN = Hh * Nn * DK;  // 524288 floats
// Native state layout [hd][m][k] flat = hd*131072 + m*16 + k (== flat h / out;
// verified rounds 2/4/6). INTERMEDIATE buffers use permuted layout
// [v][hd*16+k] = v*64 + c so the per-entry gather is one coalesced 256B load.
// NOTE (r5): cg::grid_sync ~115us/sync on gfx950 — kernel boundaries are the
// cheap grid barrier. NOTE (r7): sweep iterations are independent loads —
// split-K is useless; MLP comes from unrolling.
// Packed directed entry: (t<<13)|v; for equal v, packed order == t order ==
// numpy last-write-wins rank (t<E: (src,dst); t>=E: (dst,src)).

// ---------------------------------------------------------------------------
// Kernel 0: h_perm[v*64 + hd*16 + k] = h[hd*131072 + v*16 + k]
__global__ void permute_kernel(const float* __restrict__ h, float* __restrict__ h_perm) {
    int j = blockIdx.x * blockDim.x + threadIdx.x;   // output index, coalesced
    if (j >= XLEN) return;
    int c = j & 63, v = j >> 6;
    int hd = c >> 4, k = c & 15;
    h_perm[j] = h[hd * (Nn * DK) + v * DK + k];
}

// ---------------------------------------------------------------------------
// Kernel 1: scatter all 2E directed entries into per-row buckets (4B packed).
__global__ void scatter_kernel(const int* __restrict__ src, const int* __restrict__ dst,
                               int* __restrict__ cnt, unsigned* __restrict__ bucket) {
    int t = blockIdx.x * blockDim.x + threadIdx.x;
    if (t >= 2 * Ee) return;
    int u, v;
    if (t < Ee) { u = src[t]; v = dst[t]; }
    else        { u = dst[t - Ee]; v = src[t - Ee]; }
    int pos = atomicAdd(&cnt[u], 1);
    if (pos < CAP) bucket[u * CAP + pos] = ((unsigned)t << 13) | (unsigned)v;
}

// ---------------------------------------------------------------------------
// Kernel 2: dedup + rowsum + normalize + SWEEP 1 fused.
// One wave per row. Survivors staged in LDS; sweep 1 (x1 = s1*(a@h)+c1*h)
// computed from LDS coefficients immediately (no cross-row dependency).
__global__ void __launch_bounds__(256)
dedup_s1_kernel(const int* __restrict__ cnt, const unsigned* __restrict__ bucket,
                const float* __restrict__ e, const float* __restrict__ h_perm,
                int* __restrict__ cnt2, int* __restrict__ cols,
                float* __restrict__ val4, float* __restrict__ x1,
                float s1, float c1) {
    __shared__ unsigned lp[4][CAP];
    __shared__ int      lcol[4][CAP];     // prescaled v*64
    __shared__ float    lval[4][4 * CAP]; // [4*pos+hd]
    int w = threadIdx.x >> 6;
    int lane = threadIdx.x & 63;
    int u = blockIdx.x * 4 + w;
    int d = cnt[u]; if (d > CAP) d = CAP;

    for (int i = lane; i < d; i += 64)
        lp[w][i] = bucket[u * CAP + i];
    __syncthreads();

    // survival scan + per-head partial rowsums (lane owns entries lane, lane+64)
    bool  surv[2] = {false, false};
    int   vv[2];
    float ev[2][4];
    float s0 = 0.f, sA = 0.f, sB = 0.f, sC = 0.f;
#pragma unroll
    for (int r = 0; r < 2; r++) {
        int i = lane + 64 * r;
        if (i < d) {
            unsigned pi = lp[w][i];
            unsigned vi = pi & 8191u;
            bool alive = true;
            for (int j = 0; j < d; j++) {
                unsigned pj = lp[w][j];
                if ((pj & 8191u) == vi && pj > pi) { alive = false; break; }
            }
            surv[r] = alive;
            vv[r] = (int)vi;
            if (alive) {
                int t = (int)(pi >> 13);
                int edge = (t >= Ee) ? (t - Ee) : t;
                ev[r][0] = e[0 * Ee + edge];
                ev[r][1] = e[1 * Ee + edge];
                ev[r][2] = e[2 * Ee + edge];
                ev[r][3] = e[3 * Ee + edge];
                s0 += ev[r][0]; sA += ev[r][1]; sB += ev[r][2]; sC += ev[r][3];
            }
        }
    }
#pragma unroll
    for (int off = 32; off > 0; off >>= 1) {
        s0 += __shfl_xor(s0, off, 64);
        sA += __shfl_xor(sA, off, 64);
        sB += __shfl_xor(sB, off, 64);
        sC += __shfl_xor(sC, off, 64);
    }
    float i0 = 1.f / s0, i1 = 1.f / sA, i2 = 1.f / sB, i3 = 1.f / sC;

    // ballot-compact survivors
    unsigned long long m0 = __ballot(surv[0]);
    unsigned long long m1 = __ballot(surv[1]);
    unsigned long long below = ((unsigned long long)1 << lane) - 1;
    int base1 = __popcll(m0);
    int pos[2];
    pos[0] = __popcll(m0 & below);
    pos[1] = base1 + __popcll(m1 & below);
    int total = base1 + __popcll(m1);
#pragma unroll
    for (int r = 0; r < 2; r++) {
        if (surv[r]) {
            float f0 = ev[r][0] * i0, f1 = ev[r][1] * i1,
                  f2 = ev[r][2] * i2, f3 = ev[r][3] * i3;
            int q = u * CAP + pos[r];
            int vcol = vv[r] << 6;            // prescaled for perm layout
            cols[q] = vcol;
            val4[4 * q + 0] = f0; val4[4 * q + 1] = f1;
            val4[4 * q + 2] = f2; val4[4 * q + 3] = f3;
            lcol[w][pos[r]] = vcol;
            lval[w][4 * pos[r] + 0] = f0; lval[w][4 * pos[r] + 1] = f1;
            lval[w][4 * pos[r] + 2] = f2; lval[w][4 * pos[r] + 3] = f3;
        }
    }
    if (lane == 0) cnt2[u] = total;

    // ---- sweep 1 from LDS (wave-local; compiler orders own ds ops) ----
    int hd = lane >> 4;
    float acc = 0.f;
    for (int p = 0; p < total; p++)
        acc += lval[w][4 * p + hd] * h_perm[lcol[w][p] + lane];
    int oi = (u << 6) + lane;
    x1[oi] = s1 * acc + c1 * h_perm[oi];
}

// ---------------------------------------------------------------------------
// Kernel 3: one Horner sweep in permuted layout.  xn = s_k*(a@x) + c_k*h_perm
// One wave per row; per entry ONE coalesced 256B gather; 4x unroll for MLP.
__global__ void __launch_bounds__(256)
spmv_kernel(const int* __restrict__ cnt2, const int* __restrict__ cols,
            const float* __restrict__ val4, const float* __restrict__ x,
            const float* __restrict__ h_perm, float* __restrict__ xn,
            float s_k, float c_k) {
    int u = blockIdx.x * (blockDim.x >> 6) + (threadIdx.x >> 6);
    int lane = threadIdx.x & 63;
    int hd = lane >> 4;
    int d = cnt2[u];
    int base = u * CAP;
    float a0 = 0.f, a1 = 0.f, a2 = 0.f, a3 = 0.f;
    int p = 0;
    for (; p + 4 <= d; p += 4) {
        int q = base + p;
        int c0 = cols[q], c1_ = cols[q + 1], c2 = cols[q + 2], c3 = cols[q + 3];
        float f0 = val4[4 * q + hd];
        float f1 = val4[4 * (q + 1) + hd];
        float f2 = val4[4 * (q + 2) + hd];
        float f3 = val4[4 * (q + 3) + hd];
        a0 += f0 * x[c0 + lane];
        a1 += f1 * x[c1_ + lane];
        a2 += f2 * x[c2 + lane];
        a3 += f3 * x[c3 + lane];
    }
    for (; p < d; p++) {
        int q = base + p;
        a0 += val4[4 * q + hd] * x[cols[q] + lane];
    }
    int oi = (u << 6) + lane;
    xn[oi] = s_k * ((a0 + a1) + (a2 + a3)) + c_k * h_perm[oi];
}

// ---------------------------------------------------------------------------
// Kernel 4: final sweep — same but writes NATIVE layout d_out.
__global__ void __launch_bounds__(256)
spmv_last_kernel(const int* __restrict__ cnt2, const int* __restrict__ cols,
                 const float* __restrict__ val4, const float* __restrict__ x,
                 const float* __restrict__ h_perm, float* __restrict__ out,
                 float s_k, float c_k) {
    int u = blockIdx.x * (blockDim.x >> 6) + (threadIdx.x >> 6);
    int lane = threadIdx.x & 63;
    int hd = lane >> 4, k = lane & 15;
    int d = cnt2[u];
    int base = u * CAP;
    float a0 = 0.f, a1 = 0.f, a2 = 0.f, a3 = 0.f;
    int p = 0;
    for (; p + 4 <= d; p += 4) {
        int q = base + p;
        int c0 = cols[q], c1_ = cols[q + 1], c2 = cols[q + 2], c3 = cols[q + 3];
        float f0 = val4[4 * q + hd];
        float f1 = val4[4 * (q + 1) + hd];
        float f2 = val4[4 * (q + 2) + hd];
        float f3 = val4[4 * (q + 3) + hd];
        a0 += f0 * x[c0 + lane];
        a1 += f1 * x[c1_ + lane];
        a2 += f2 * x[c2 + lane];
        a3 += f3 * x[c3 + lane];
    }
    for (; p < d; p++) {
        int q = base + p;
        a0 += val4[4 * q + hd] * x[cols[q] + lane];
    }
    float r = s_k * ((a0 + a1) + (a2 + a3)) + c_k * h_perm[(u << 6) + lane];
    out[hd * (Nn * DK) + u * DK + k] = r;   // native layout
}

// ---------------------------------------------------------------------------
extern "C" void kernel_launch(void* const* d_in, const int* in_sizes, int n_in,
                              void* d_out, int out_size, void* d_ws, size_t ws_size,
                              hipStream_t stream) {
    const float* h = (const float*)d_in[0];
    const float* e = (const float*)d_in[1];
    const int* src = (const int*)d_in[2];
    const int* dst = (const int*)d_in[3];
    float* out = (float*)d_out;

    // Workspace carve-up (~31 MB)
    char* ws = (char*)d_ws;
    size_t off = 0;
    auto alloc = [&](size_t bytes) -> void* {
        void* p = ws + off;
        off = (off + bytes + 255) & ~(size_t)255;
        return p;
    };
    int*      cnt    = (int*)     alloc((size_t)Nn * 4);
    int*      cnt2   = (int*)     alloc((size_t)Nn * 4);
    unsigned* bucket = (unsigned*)alloc((size_t)Nn * CAP * 4);      // 4 MB
    int*      cols   = (int*)     alloc((size_t)Nn * CAP * 4);      // 4 MB
    float*    val4   = (float*)   alloc((size_t)Nn * CAP * 4 * 4);  // 16 MB
    float*    h_perm = (float*)   alloc((size_t)XLEN * 4);          // 2 MB
    float*    bufA   = (float*)   alloc((size_t)XLEN * 4);          // 2 MB
    float*    bufB   = (float*)   alloc((size_t)XLEN * 4);          // 2 MB

    const int tpb = 256;

    hipMemsetAsync(cnt, 0, (size_t)Nn * 4, stream);
    permute_kernel<<<XLEN / tpb, tpb, 0, stream>>>(h, h_perm);
    scatter_kernel<<<(2 * Ee) / tpb, tpb, 0, stream>>>(src, dst, cnt, bucket);

    // Horner: r1 = (1/720) a h + (1/120) h; r_{k+1} = a r_k + c_k h; out = r6
    const float s_k[6] = {1.f / 720.f, 1.f, 1.f, 1.f, 1.f, 1.f};
    const float c_k[6] = {1.f / 120.f, 1.f / 24.f, 1.f / 6.f, 0.5f, 1.f, 1.f};

    dedup_s1_kernel<<<Nn / 4, tpb, 0, stream>>>(cnt, bucket, e, h_perm, cnt2,
                                                cols, val4, bufA, s_k[0], c_k[0]);
    spmv_kernel<<<Nn / 4, tpb, 0, stream>>>(cnt2, cols, val4, bufA, h_perm, bufB, s_k[1], c_k[1]);
    spmv_kernel<<<Nn / 4, tpb, 0, stream>>>(cnt2, cols, val4, bufB, h_perm, bufA, s_k[2], c_k[2]);
    spmv_kernel<<<Nn / 4, tpb, 0, stream>>>(cnt2, cols, val4, bufA, h_perm, bufB, s_k[3], c_k[3]);
    spmv_kernel<<<Nn / 4, tpb, 0, stream>>>(cnt2, cols, val4, bufB, h_perm, bufA, s_k[4], c_k[4]);
    spmv_last_kernel<<<Nn / 4, tpb, 0, stream>>>(cnt2, cols, val4, bufA, h_perm, out, s_k[5], c_k[5]);
}